// Round 9
// baseline (90.629 us; speedup 1.0000x reference)
//
#include <hip/hip_runtime.h>

#define B_SZ 2048
#define D_IN 256
#define L_N 48
#define H_N 256
#define O_N 10
#define WROW 303      // D + L - 1
#define LEAF_N 12336  // L*(D+1)
#define KC 2304       // L*L
#define KHAT 2352     // KC + L (valid cols)
#define KPAD 2560     // padded K (multiple of 64)

using short8 = __attribute__((ext_vector_type(8))) short;
using f32x4  = __attribute__((ext_vector_type(4))) float;

// split fp32 into bf16 hi (truncate) + bf16 lo (truncate of residual)
__device__ inline void bf16_split(float v, unsigned short& h, unsigned short& l) {
  unsigned bits = __float_as_uint(v);
  h = (unsigned short)(bits >> 16);
  float hf = __uint_as_float(bits & 0xFFFF0000u);
  float r = v - hf;
  l = (unsigned short)(__float_as_uint(r) >> 16);
}

// ---------------------------------------------------------------------------
// Kernel 1: merged phase-1. blocks [0,768): Ghat partial GEMM
//   Gp[z][h][i*48+k] = sum_{d in chunk z} W[k,d]*Wb0[h,i*257+d]
// blocks [768,1152): P[b,i] = dot(x[b,:], W[i,0:256])
// ---------------------------------------------------------------------------
__global__ __launch_bounds__(256) void k_phase1(const float* __restrict__ W,
                                                const float* __restrict__ Wb0,
                                                const float* __restrict__ x,
                                                float* __restrict__ Gp,
                                                float* __restrict__ P) {
  const int bid = blockIdx.x;
  const int t = threadIdx.x;
  if (bid < 768) {
    const int i  = bid % 48;              // layer
    const int rest = bid / 48;            // 0..15
    const int h0 = (rest & 3) * 64;       // h tile
    const int dc = (rest >> 2) * 64;      // d chunk
    __shared__ float At[64][68];          // [d][h]
    __shared__ float Bt[64][68];          // [d][k] (k>=48 zero)
    const int tn = t & 15, tm = t >> 4;
    const int sr = t & 3, sc = t >> 2;    // staging: 4 rows x 64 cols
#pragma unroll
    for (int j = 0; j < 16; ++j) {
      int r = sr + j * 4;
      At[sc][r] = Wb0[(size_t)(h0 + r) * LEAF_N + i * 257 + dc + sc];
      Bt[sc][r] = (r < 48) ? W[r * WROW + dc + sc] : 0.f;
    }
    __syncthreads();
    float acc[4][4] = {};
#pragma unroll 8
    for (int d = 0; d < 64; ++d) {
      float4 av = *(const float4*)&At[d][tm * 4];
      float4 bv = *(const float4*)&Bt[d][tn * 4];
      float aa[4] = {av.x, av.y, av.z, av.w};
      float bb[4] = {bv.x, bv.y, bv.z, bv.w};
#pragma unroll
      for (int ii = 0; ii < 4; ++ii)
#pragma unroll
        for (int jj = 0; jj < 4; ++jj) acc[ii][jj] += aa[ii] * bb[jj];
    }
    if (tn < 12) {
      float* gz = Gp + (size_t)(rest >> 2) * (H_N * KC);
#pragma unroll
      for (int ii = 0; ii < 4; ++ii)
        *(float4*)&gz[(size_t)(h0 + tm * 4 + ii) * KC + i * 48 + tn * 4] =
            make_float4(acc[ii][0], acc[ii][1], acc[ii][2], acc[ii][3]);
    }
  } else {
    int idx = (bid - 768) * 256 + t;  // 0..98303
    int b = idx / 48, i = idx - b * 48;
    const float* xr = x + (size_t)b * D_IN;
    const float* wr = W + (size_t)i * WROW;
    float acc = 0.f;
#pragma unroll 4
    for (int d = 0; d < 256; ++d) acc += xr[d] * wr[d];
    P[idx] = acc;
  }
}

// ---------------------------------------------------------------------------
// Kernel 2: merged mid-phase.
// blocks [0,256): gcomb -- combine Gp partials -> bf16 hi/lo Ghat (+offs,pad)
// blocks [256,768): seq  -- 4 independent waves, one batch row each
// ---------------------------------------------------------------------------
__global__ __launch_bounds__(256) void k_mid(const float* __restrict__ Gp,
                                             const float* __restrict__ Wb0,
                                             const float* __restrict__ W,
                                             const float* __restrict__ bvec,
                                             const float* __restrict__ P,
                                             unsigned short* __restrict__ Gh,
                                             unsigned short* __restrict__ Gl,
                                             unsigned short* __restrict__ Ch,
                                             unsigned short* __restrict__ Cl,
                                             float* __restrict__ mask_out) {
  const int bid = blockIdx.x;
  const int t = threadIdx.x;
  if (bid < 256) {
    const int h = bid;
    for (int e = t; e < KC / 4; e += 256) {
      float4 s0 = *(const float4*)&Gp[(size_t)h * KC + e * 4];
      float4 s1 = *(const float4*)&Gp[(size_t)(H_N + h) * KC + e * 4];
      float4 s2 = *(const float4*)&Gp[(size_t)(2 * H_N + h) * KC + e * 4];
      float4 s3 = *(const float4*)&Gp[(size_t)(3 * H_N + h) * KC + e * 4];
      float v[4] = {s0.x + s1.x + s2.x + s3.x, s0.y + s1.y + s2.y + s3.y,
                    s0.z + s1.z + s2.z + s3.z, s0.w + s1.w + s2.w + s3.w};
      ushort4 h4, l4;
      bf16_split(v[0], h4.x, l4.x);
      bf16_split(v[1], h4.y, l4.y);
      bf16_split(v[2], h4.z, l4.z);
      bf16_split(v[3], h4.w, l4.w);
      *(ushort4*)&Gh[(size_t)h * KPAD + e * 4] = h4;
      *(ushort4*)&Gl[(size_t)h * KPAD + e * 4] = l4;
    }
    if (t < 48) {
      unsigned short hh, ll;
      bf16_split(Wb0[(size_t)h * LEAF_N + t * 257 + 256], hh, ll);
      Gh[(size_t)h * KPAD + KC + t] = hh;
      Gl[(size_t)h * KPAD + KC + t] = ll;
    }
    for (int e = KHAT + t; e < KPAD; e += 256) {
      Gh[(size_t)h * KPAD + e] = 0;
      Gl[(size_t)h * KPAD + e] = 0;
    }
    return;
  }
  // ---- seq part: wave-independent, one batch row per wave ----
  const int b = (bid - 256) * 4 + (t >> 6);
  const int lane = t & 63;

  float whr[47];
#pragma unroll
  for (int k = 0; k < 47; ++k)
    whr[k] = (lane < 48) ? W[lane * WROW + 256 + k] : 0.f;

  float Preg = (lane < 48) ? P[b * 48 + lane] : 0.f;
  float Pb = Preg + ((lane < 48) ? bvec[lane] : 0.f);

  float accA = 0.f, accB = 0.f;
  float offs_lane = 0.f;
  int d_lane = 0;
#pragma unroll
  for (int i = 0; i < 48; ++i) {
    float z = Pb + accA;
    float u = Preg + accB;
    float a_i = fmaxf(z, 0.f);
    bool dpos = z > 0.f;
    float o_i = dpos ? u : 0.f;
    if (lane == i) {
      d_lane = dpos ? 1 : 0;
      offs_lane = a_i - o_i;
    }
    float ab = __shfl(a_i, i);
    float ob = __shfl(o_i, i);
    if (i < 47) {
      accA += whr[i] * ab;
      accB += whr[i] * ob;
    }
  }
  unsigned long long dmask = __ballot(d_lane);

  float s[48];
  s[0] = ((dmask & 1ULL) && lane == 0) ? 1.f : 0.f;
#pragma unroll
  for (int i = 1; i < 48; ++i) {
    if ((dmask >> i) & 1ULL) {
      const float* wrow = W + i * WROW + 256;  // wave-uniform scalar loads
      float t0 = (lane == i) ? 1.f : 0.f;
      float t1 = 0.f, t2 = 0.f, t3 = 0.f;
      int k = 0;
#pragma unroll
      for (; k + 3 < i; k += 4) {
        t0 += wrow[k + 0] * s[k + 0];
        t1 += wrow[k + 1] * s[k + 1];
        t2 += wrow[k + 2] * s[k + 2];
        t3 += wrow[k + 3] * s[k + 3];
      }
#pragma unroll
      for (; k < i; ++k) t0 += wrow[k] * s[k];
      s[i] = (t0 + t1) + (t2 + t3);
    } else {
      s[i] = 0.f;
    }
  }

  size_t base = (size_t)b * KPAD;
  if (lane < 48) {
#pragma unroll
    for (int i = 0; i < 48; ++i) {
      unsigned short h, l;
      bf16_split(s[i], h, l);
      Ch[base + i * 48 + lane] = h;
      Cl[base + i * 48 + lane] = l;
    }
    unsigned short h, l;
    bf16_split(offs_lane, h, l);
    Ch[base + KC + lane] = h;
    Cl[base + KC + lane] = l;
    mask_out[b * 48 + lane] = d_lane ? 1.f : 0.f;
  }
  for (int e = lane; e < 208; e += 64) {
    Ch[base + KHAT + e] = 0;
    Cl[base + KHAT + e] = 0;
  }
}

// ---------------------------------------------------------------------------
// Kernel 4: big GEMM via bf16 MFMA 3-term split. 8 waves (512 thr), each
// wave owns a 16x32 output tile. A-fragments read DIRECTLY from global
// (wave-private, used once -> LDS staging was pure overhead); only B (shared
// x8 waves) staged in LDS. XCD-chunk-swizzled. LDS row stride 88 shorts.
// ---------------------------------------------------------------------------
#define LDSP 88
__global__ __launch_bounds__(512) void k_gemm_bf16(
    const unsigned short* __restrict__ Ah, const unsigned short* __restrict__ Al,
    const unsigned short* __restrict__ Bh, const unsigned short* __restrict__ Bl,
    float* __restrict__ part) {
  int flat = blockIdx.x + 32 * blockIdx.y + 128 * blockIdx.z;  // 0..511
  int id = (flat & 7) * 64 + (flat >> 3);                      // XCD chunks
  const int bz = id & 3, by = (id >> 2) & 3, bx = id >> 4;
  const int m0 = bx * 64;
  const int n0 = by * 64;
  const int k0 = bz * 640;
  float* dst = part + (size_t)bz * ((size_t)B_SZ * H_N);
  __shared__ unsigned short BhL[64 * LDSP], BlL[64 * LDSP];
  const int t = threadIdx.x;
  const int lane = t & 63;
  const int w = t >> 6;        // 0..7
  const int wm = w & 3;        // m strip (16 rows)
  const int wn = w >> 1 & 2;   // unused placeholder (see below)
  const int wnh = w >> 2;      // n half (32 cols)
  const int fr = lane & 15;
  const int fq = lane >> 4;
  const int srow = t >> 3, sko = (t & 7) * 8;  // B staging: 512 slots
  f32x4 acc[2] = {};
  (void)wn;
  for (int it = 0; it < 10; ++it) {
    int kb = k0 + it * 64;
    size_t gb = (size_t)(n0 + srow) * KPAD + kb + sko;
    *(short8*)&BhL[srow * LDSP + sko] = *(const short8*)&Bh[gb];
    *(short8*)&BlL[srow * LDSP + sko] = *(const short8*)&Bl[gb];
    __syncthreads();
#pragma unroll
    for (int ks = 0; ks < 2; ++ks) {
      size_t ga = (size_t)(m0 + wm * 16 + fr) * KPAD + kb + fq * 8 + ks * 32;
      short8 ah = *(const short8*)&Ah[ga];
      short8 al = *(const short8*)&Al[ga];
#pragma unroll
      for (int nt = 0; nt < 2; ++nt) {
        int boff = (wnh * 32 + nt * 16 + fr) * LDSP + fq * 8 + ks * 32;
        short8 bh = *(const short8*)&BhL[boff];
        short8 bl = *(const short8*)&BlL[boff];
        acc[nt] = __builtin_amdgcn_mfma_f32_16x16x32_bf16(ah, bh, acc[nt], 0, 0, 0);
        acc[nt] = __builtin_amdgcn_mfma_f32_16x16x32_bf16(al, bh, acc[nt], 0, 0, 0);
        acc[nt] = __builtin_amdgcn_mfma_f32_16x16x32_bf16(ah, bl, acc[nt], 0, 0, 0);
      }
    }
    __syncthreads();
  }
  // C layout: col = lane&15, row = (lane>>4)*4 + reg  [m89-verified]
  int mrow = m0 + wm * 16 + fq * 4;
#pragma unroll
  for (int nt = 0; nt < 2; ++nt) {
    int ncol = n0 + wnh * 32 + nt * 16 + fr;
#pragma unroll
    for (int r = 0; r < 4; ++r)
      dst[(size_t)(mrow + r) * H_N + ncol] = acc[nt][r];
  }
}

// ---------------------------------------------------------------------------
// Kernel 5: h1 = relu( relu(sum_z part_z + bb0) @ Wb1^T + bb1 ), fused
// reduce+bias+relu in A-staging. XCD-chunk-swizzled. BM=64 BN=32.
// ---------------------------------------------------------------------------
__global__ __launch_bounds__(256) void k_gemm2f(const float* __restrict__ part,
                                                const float* __restrict__ bb0,
                                                const float* __restrict__ Bm,
                                                const float* __restrict__ bias,
                                                float* __restrict__ h1) {
  int flat = blockIdx.x + 32 * blockIdx.y;      // 0..255
  int id = (flat & 7) * 32 + (flat >> 3);       // XCD chunks, x slowest
  const int m0 = (id >> 3) * 64;
  const int n0 = (id & 7) * 32;
  const size_t BH = (size_t)B_SZ * H_N;
  __shared__ float At[32][68];
  __shared__ float Bt[32][36];
  const int t = threadIdx.x;
  const int tn = t & 7, tmq = t >> 3;
  float acc[2][4] = {};
  for (int it = 0; it < 8; ++it) {
    int kb = it * 32;
#pragma unroll
    for (int j = 0; j < 2; ++j) {
      int c = t + j * 256;
      int m = c >> 3, c4 = c & 7;
      size_t base = (size_t)(m0 + m) * H_N + kb + c4 * 4;
      float4 v0 = *(const float4*)&part[base];
      float4 v1 = *(const float4*)&part[base + BH];
      float4 v2 = *(const float4*)&part[base + 2 * BH];
      float4 v3 = *(const float4*)&part[base + 3 * BH];
      float4 bi = *(const float4*)&bb0[kb + c4 * 4];
      At[c4 * 4 + 0][m] = fmaxf(v0.x + v1.x + v2.x + v3.x + bi.x, 0.f);
      At[c4 * 4 + 1][m] = fmaxf(v0.y + v1.y + v2.y + v3.y + bi.y, 0.f);
      At[c4 * 4 + 2][m] = fmaxf(v0.z + v1.z + v2.z + v3.z + bi.z, 0.f);
      At[c4 * 4 + 3][m] = fmaxf(v0.w + v1.w + v2.w + v3.w + bi.w, 0.f);
    }
    {
      int m = t >> 3, c4 = t & 7;
      if (m < 32) {
        float4 v = *(const float4*)&Bm[(size_t)(n0 + m) * H_N + kb + c4 * 4];
        Bt[c4 * 4 + 0][m] = v.x;
        Bt[c4 * 4 + 1][m] = v.y;
        Bt[c4 * 4 + 2][m] = v.z;
        Bt[c4 * 4 + 3][m] = v.w;
      }
    }
    __syncthreads();
#pragma unroll
    for (int k = 0; k < 32; ++k) {
      float2 av = *(const float2*)&At[k][tmq * 2];
      float4 bv = *(const float4*)&Bt[k][tn * 4];
      acc[0][0] += av.x * bv.x; acc[0][1] += av.x * bv.y;
      acc[0][2] += av.x * bv.z; acc[0][3] += av.x * bv.w;
      acc[1][0] += av.y * bv.x; acc[1][1] += av.y * bv.y;
      acc[1][2] += av.y * bv.z; acc[1][3] += av.y * bv.w;
    }
    __syncthreads();
  }
#pragma unroll
  for (int ii = 0; ii < 2; ++ii) {
    int m = m0 + tmq * 2 + ii;
    float* o = h1 + (size_t)m * H_N + n0 + tn * 4;
    float4 v;
    v.x = fmaxf(acc[ii][0] + bias[n0 + tn * 4 + 0], 0.f);
    v.y = fmaxf(acc[ii][1] + bias[n0 + tn * 4 + 1], 0.f);
    v.z = fmaxf(acc[ii][2] + bias[n0 + tn * 4 + 2], 0.f);
    v.w = fmaxf(acc[ii][3] + bias[n0 + tn * 4 + 3], 0.f);
    *(float4*)o = v;
  }
}

// ---------------------------------------------------------------------------
// Kernel 6: out[b,:] = h1[b,:] @ Wout^T + bout. One wave per batch row.
// ---------------------------------------------------------------------------
__global__ __launch_bounds__(256) void k_out(const float* __restrict__ h1,
                                             const float* __restrict__ Wout,
                                             const float* __restrict__ bout,
                                             float* __restrict__ out) {
  int w = threadIdx.x >> 6, lane = threadIdx.x & 63;
  int b = blockIdx.x * 4 + w;
  const float* hr = h1 + (size_t)b * H_N;
  float h[4];
#pragma unroll
  for (int j = 0; j < 4; ++j) h[j] = hr[lane + 64 * j];
  float acc[10];
#pragma unroll
  for (int o = 0; o < 10; ++o) {
    float s = 0.f;
#pragma unroll
    for (int j = 0; j < 4; ++j) s += h[j] * Wout[o * H_N + lane + 64 * j];
#pragma unroll
    for (int m = 32; m >= 1; m >>= 1) s += __shfl_xor(s, m);
    acc[o] = s;
  }
  if (lane == 0) {
#pragma unroll
    for (int o = 0; o < 10; ++o) out[(size_t)b * O_N + o] = acc[o] + bout[o];
  }
}

// ---------------------------------------------------------------------------
extern "C" void kernel_launch(void* const* d_in, const int* in_sizes, int n_in,
                              void* d_out, int out_size, void* d_ws,
                              size_t ws_size, hipStream_t stream) {
  (void)in_sizes; (void)n_in; (void)out_size; (void)ws_size;
  const float* x    = (const float*)d_in[0];
  const float* W    = (const float*)d_in[1];
  const float* bvec = (const float*)d_in[2];
  const float* Wb0  = (const float*)d_in[3];
  const float* bb0  = (const float*)d_in[4];
  const float* Wb1  = (const float*)d_in[5];
  const float* bb1  = (const float*)d_in[6];
  const float* Wout = (const float*)d_in[7];
  const float* bout = (const float*)d_in[8];

  float* out   = (float*)d_out;     // B*10
  float* masks = out + B_SZ * O_N;  // B*48

  char* wsb = (char*)d_ws;
  float* P = (float*)wsb;                                   // 393,216 B
  unsigned short* Ch = (unsigned short*)(wsb + 393216);     // B*KPAD us
  unsigned short* Cl = Ch + (size_t)B_SZ * KPAD;
  unsigned short* Gh = Cl + (size_t)B_SZ * KPAD;            // H*KPAD us
  unsigned short* Gl = Gh + (size_t)H_N * KPAD;
  float* part = (float*)(Gl + (size_t)H_N * KPAD);          // 4*B*H f32
  float* Gp = part + 4 * (size_t)B_SZ * H_N;                // 4*H*KC f32
  float* h1 = Gp;                                           // alias (Gp dead)
  // total ~42 MB

  k_phase1<<<dim3(1152), 256, 0, stream>>>(W, Wb0, x, Gp, P);
  k_mid<<<dim3(768), 256, 0, stream>>>(Gp, Wb0, W, bvec, P, Gh, Gl, Ch, Cl,
                                       masks);
  k_gemm_bf16<<<dim3(32, 4, 4), 512, 0, stream>>>(Ch, Cl, Gh, Gl, part);
  k_gemm2f<<<dim3(32, 8), 256, 0, stream>>>(part, bb0, Wb1, bb1, h1);
  k_out<<<dim3(512), 256, 0, stream>>>(h1, Wout, bout, out);
}

// Round 10
// 75.832 us; speedup vs baseline: 1.1951x; 1.1951x over previous
//
#include <hip/hip_runtime.h>

#define B_SZ 2048
#define D_IN 256
#define L_N 48
#define H_N 256
#define O_N 10
#define WROW 303      // D + L - 1
#define LEAF_N 12336  // L*(D+1)
#define KC 2304       // L*L (Gp full layout)
#define KTRI 1176     // 48*49/2 packed lower-tri cols
#define KH2 1224      // KTRI + 48 offs cols
#define KPAD2 1280    // padded K (20 x 64)

using short8 = __attribute__((ext_vector_type(8))) short;
using f32x4  = __attribute__((ext_vector_type(4))) float;

// split fp32 into bf16 hi (truncate) + bf16 lo (truncate of residual)
__device__ inline void bf16_split(float v, unsigned short& h, unsigned short& l) {
  unsigned bits = __float_as_uint(v);
  h = (unsigned short)(bits >> 16);
  float hf = __uint_as_float(bits & 0xFFFF0000u);
  float r = v - hf;
  l = (unsigned short)(__float_as_uint(r) >> 16);
}

// ---------------------------------------------------------------------------
// Kernel 1: merged phase-1. blocks [0,768): Ghat partial GEMM
//   Gp[z][h][i*48+k] = sum_{d in chunk z} W[k,d]*Wb0[h,i*257+d]
// blocks [768,1152): P[b,i] = dot(x[b,:], W[i,0:256])
// ---------------------------------------------------------------------------
__global__ __launch_bounds__(256) void k_phase1(const float* __restrict__ W,
                                                const float* __restrict__ Wb0,
                                                const float* __restrict__ x,
                                                float* __restrict__ Gp,
                                                float* __restrict__ P) {
  const int bid = blockIdx.x;
  const int t = threadIdx.x;
  if (bid < 768) {
    const int i  = bid % 48;              // layer
    const int rest = bid / 48;            // 0..15
    const int h0 = (rest & 3) * 64;       // h tile
    const int dc = (rest >> 2) * 64;      // d chunk
    __shared__ float At[64][68];          // [d][h]
    __shared__ float Bt[64][68];          // [d][k] (k>=48 zero)
    const int tn = t & 15, tm = t >> 4;
    const int sr = t & 3, sc = t >> 2;    // staging: 4 rows x 64 cols
#pragma unroll
    for (int j = 0; j < 16; ++j) {
      int r = sr + j * 4;
      At[sc][r] = Wb0[(size_t)(h0 + r) * LEAF_N + i * 257 + dc + sc];
      Bt[sc][r] = (r < 48) ? W[r * WROW + dc + sc] : 0.f;
    }
    __syncthreads();
    float acc[4][4] = {};
#pragma unroll 8
    for (int d = 0; d < 64; ++d) {
      float4 av = *(const float4*)&At[d][tm * 4];
      float4 bv = *(const float4*)&Bt[d][tn * 4];
      float aa[4] = {av.x, av.y, av.z, av.w};
      float bb[4] = {bv.x, bv.y, bv.z, bv.w};
#pragma unroll
      for (int ii = 0; ii < 4; ++ii)
#pragma unroll
        for (int jj = 0; jj < 4; ++jj) acc[ii][jj] += aa[ii] * bb[jj];
    }
    if (tn < 12) {
      float* gz = Gp + (size_t)(rest >> 2) * (H_N * KC);
#pragma unroll
      for (int ii = 0; ii < 4; ++ii)
        *(float4*)&gz[(size_t)(h0 + tm * 4 + ii) * KC + i * 48 + tn * 4] =
            make_float4(acc[ii][0], acc[ii][1], acc[ii][2], acc[ii][3]);
    }
  } else {
    int idx = (bid - 768) * 256 + t;  // 0..98303
    int b = idx / 48, i = idx - b * 48;
    const float* xr = x + (size_t)b * D_IN;
    const float* wr = W + (size_t)i * WROW;
    float acc = 0.f;
#pragma unroll 4
    for (int d = 0; d < 256; ++d) acc += xr[d] * wr[d];
    P[idx] = acc;
  }
}

// ---------------------------------------------------------------------------
// Kernel 2: merged mid-phase.
// blocks [0,256): gcomb -- sum Gp partials, pack lower-tri j=i(i+1)/2+k,
//                 bf16 hi/lo Ghat (+offs col, pad)
// blocks [256,768): seq -- 4 independent waves, one batch row each
// ---------------------------------------------------------------------------
__global__ __launch_bounds__(256) void k_mid(const float* __restrict__ Gp,
                                             const float* __restrict__ Wb0,
                                             const float* __restrict__ W,
                                             const float* __restrict__ bvec,
                                             const float* __restrict__ P,
                                             unsigned short* __restrict__ Gh,
                                             unsigned short* __restrict__ Gl,
                                             unsigned short* __restrict__ Ch,
                                             unsigned short* __restrict__ Cl,
                                             float* __restrict__ mask_out) {
  const int bid = blockIdx.x;
  const int t = threadIdx.x;
  if (bid < 256) {
    const int h = bid;
    for (int j = t; j < KTRI; j += 256) {
      // j -> (i,k), k<=i: i = row of triangle
      int i = (int)((sqrtf((float)(8 * j + 1)) - 1.f) * 0.5f);
      while ((i + 1) * (i + 2) / 2 <= j) ++i;
      while (i * (i + 1) / 2 > j) --i;
      int k = j - i * (i + 1) / 2;
      size_t g = (size_t)h * KC + i * 48 + k;
      float v = Gp[g] + Gp[(size_t)H_N * KC + g] +
                Gp[2 * (size_t)H_N * KC + g] + Gp[3 * (size_t)H_N * KC + g];
      unsigned short hh, ll;
      bf16_split(v, hh, ll);
      Gh[(size_t)h * KPAD2 + j] = hh;
      Gl[(size_t)h * KPAD2 + j] = ll;
    }
    if (t < 48) {  // offs col
      unsigned short hh, ll;
      bf16_split(Wb0[(size_t)h * LEAF_N + t * 257 + 256], hh, ll);
      Gh[(size_t)h * KPAD2 + KTRI + t] = hh;
      Gl[(size_t)h * KPAD2 + KTRI + t] = ll;
    }
    for (int e = KH2 + t; e < KPAD2; e += 256) {
      Gh[(size_t)h * KPAD2 + e] = 0;
      Gl[(size_t)h * KPAD2 + e] = 0;
    }
    return;
  }
  // ---- seq part: wave-independent, one batch row per wave ----
  const int b = (bid - 256) * 4 + (t >> 6);
  const int lane = t & 63;

  float whr[47];
#pragma unroll
  for (int k = 0; k < 47; ++k)
    whr[k] = (lane < 48) ? W[lane * WROW + 256 + k] : 0.f;

  float Preg = (lane < 48) ? P[b * 48 + lane] : 0.f;
  float Pb = Preg + ((lane < 48) ? bvec[lane] : 0.f);

  float accA = 0.f, accB = 0.f;
  float offs_lane = 0.f;
  int d_lane = 0;
#pragma unroll
  for (int i = 0; i < 48; ++i) {
    float z = Pb + accA;
    float u = Preg + accB;
    float a_i = fmaxf(z, 0.f);
    bool dpos = z > 0.f;
    float o_i = dpos ? u : 0.f;
    if (lane == i) {
      d_lane = dpos ? 1 : 0;
      offs_lane = a_i - o_i;
    }
    float ab = __shfl(a_i, i);
    float ob = __shfl(o_i, i);
    if (i < 47) {
      accA += whr[i] * ab;
      accB += whr[i] * ob;
    }
  }
  unsigned long long dmask = __ballot(d_lane);

  float s[48];
  s[0] = ((dmask & 1ULL) && lane == 0) ? 1.f : 0.f;
#pragma unroll
  for (int i = 1; i < 48; ++i) {
    if ((dmask >> i) & 1ULL) {
      const float* wrow = W + i * WROW + 256;  // wave-uniform scalar loads
      float t0 = (lane == i) ? 1.f : 0.f;
      float t1 = 0.f, t2 = 0.f, t3 = 0.f;
      int k = 0;
#pragma unroll
      for (; k + 3 < i; k += 4) {
        t0 += wrow[k + 0] * s[k + 0];
        t1 += wrow[k + 1] * s[k + 1];
        t2 += wrow[k + 2] * s[k + 2];
        t3 += wrow[k + 3] * s[k + 3];
      }
#pragma unroll
      for (; k < i; ++k) t0 += wrow[k] * s[k];
      s[i] = (t0 + t1) + (t2 + t3);
    } else {
      s[i] = 0.f;
    }
  }

  // packed stores: for i >= lane, j = i(i+1)/2 + lane (coalesced per i)
  size_t base = (size_t)b * KPAD2;
  if (lane < 48) {
#pragma unroll
    for (int i = 0; i < 48; ++i) {
      if (lane <= i) {
        unsigned short h, l;
        bf16_split(s[i], h, l);
        Ch[base + i * (i + 1) / 2 + lane] = h;
        Cl[base + i * (i + 1) / 2 + lane] = l;
      }
    }
    unsigned short h, l;
    bf16_split(offs_lane, h, l);
    Ch[base + KTRI + lane] = h;
    Cl[base + KTRI + lane] = l;
    mask_out[b * 48 + lane] = d_lane ? 1.f : 0.f;
  }
  for (int e = KH2 + lane; e < KPAD2; e += 64) {
    Ch[base + e] = 0;
    Cl[base + e] = 0;
  }
}

// ---------------------------------------------------------------------------
// Kernel 3: big GEMM via bf16 MFMA 3-term split (R8-proven structure:
// 4 waves, LDS-staged A+B, LDSP=88). K=1280 split 4x320 (5 iters).
// XCD-chunk-swizzled: id=(flat%8)*64+flat/8.
// ---------------------------------------------------------------------------
#define LDSP 88
__global__ __launch_bounds__(256) void k_gemm_bf16(
    const unsigned short* __restrict__ Ah, const unsigned short* __restrict__ Al,
    const unsigned short* __restrict__ Bh, const unsigned short* __restrict__ Bl,
    float* __restrict__ part) {
  int flat = blockIdx.x + 32 * blockIdx.y + 128 * blockIdx.z;  // 0..511
  int id = (flat & 7) * 64 + (flat >> 3);                      // XCD chunks
  const int bz = id & 3, by = (id >> 2) & 3, bx = id >> 4;
  const int m0 = bx * 64;
  const int n0 = by * 64;
  const int k0 = bz * 320;
  float* dst = part + (size_t)bz * ((size_t)B_SZ * H_N);
  __shared__ unsigned short AhL[64 * LDSP], AlL[64 * LDSP];
  __shared__ unsigned short BhL[64 * LDSP], BlL[64 * LDSP];
  const int t = threadIdx.x;
  const int lane = t & 63;
  const int w = t >> 6;
  const int fr = lane & 15;
  const int fq = lane >> 4;
  f32x4 acc[4] = {};
  for (int it = 0; it < 5; ++it) {
    int kb = k0 + it * 64;
#pragma unroll
    for (int j = 0; j < 2; ++j) {
      int c = t + j * 256;
      int row = c >> 3, ko = (c & 7) * 8;
      size_t ga = (size_t)(m0 + row) * KPAD2 + kb + ko;
      size_t gb = (size_t)(n0 + row) * KPAD2 + kb + ko;
      *(short8*)&AhL[row * LDSP + ko] = *(const short8*)&Ah[ga];
      *(short8*)&AlL[row * LDSP + ko] = *(const short8*)&Al[ga];
      *(short8*)&BhL[row * LDSP + ko] = *(const short8*)&Bh[gb];
      *(short8*)&BlL[row * LDSP + ko] = *(const short8*)&Bl[gb];
    }
    __syncthreads();
#pragma unroll
    for (int ks = 0; ks < 2; ++ks) {
      int aoff = (w * 16 + fr) * LDSP + fq * 8 + ks * 32;
      short8 ah = *(const short8*)&AhL[aoff];
      short8 al = *(const short8*)&AlL[aoff];
#pragma unroll
      for (int nt = 0; nt < 4; ++nt) {
        int boff = (nt * 16 + fr) * LDSP + fq * 8 + ks * 32;
        short8 bh = *(const short8*)&BhL[boff];
        short8 bl = *(const short8*)&BlL[boff];
        acc[nt] = __builtin_amdgcn_mfma_f32_16x16x32_bf16(ah, bh, acc[nt], 0, 0, 0);
        acc[nt] = __builtin_amdgcn_mfma_f32_16x16x32_bf16(al, bh, acc[nt], 0, 0, 0);
        acc[nt] = __builtin_amdgcn_mfma_f32_16x16x32_bf16(ah, bl, acc[nt], 0, 0, 0);
      }
    }
    __syncthreads();
  }
  // C layout: col = lane&15, row = (lane>>4)*4 + reg  [m89-verified]
  int mrow = m0 + w * 16 + fq * 4;
#pragma unroll
  for (int nt = 0; nt < 4; ++nt) {
    int ncol = n0 + nt * 16 + fr;
#pragma unroll
    for (int r = 0; r < 4; ++r)
      dst[(size_t)(mrow + r) * H_N + ncol] = acc[nt][r];
  }
}

// ---------------------------------------------------------------------------
// Kernel 4: h1 = relu( relu(sum_z part_z + bb0) @ Wb1^T + bb1 ), fused
// reduce+bias+relu in A-staging. XCD-chunk-swizzled. BM=64 BN=32.
// ---------------------------------------------------------------------------
__global__ __launch_bounds__(256) void k_gemm2f(const float* __restrict__ part,
                                                const float* __restrict__ bb0,
                                                const float* __restrict__ Bm,
                                                const float* __restrict__ bias,
                                                float* __restrict__ h1) {
  int flat = blockIdx.x + 32 * blockIdx.y;      // 0..255
  int id = (flat & 7) * 32 + (flat >> 3);       // XCD chunks, x slowest
  const int m0 = (id >> 3) * 64;
  const int n0 = (id & 7) * 32;
  const size_t BH = (size_t)B_SZ * H_N;
  __shared__ float At[32][68];
  __shared__ float Bt[32][36];
  const int t = threadIdx.x;
  const int tn = t & 7, tmq = t >> 3;
  float acc[2][4] = {};
  for (int it = 0; it < 8; ++it) {
    int kb = it * 32;
#pragma unroll
    for (int j = 0; j < 2; ++j) {
      int c = t + j * 256;
      int m = c >> 3, c4 = c & 7;
      size_t base = (size_t)(m0 + m) * H_N + kb + c4 * 4;
      float4 v0 = *(const float4*)&part[base];
      float4 v1 = *(const float4*)&part[base + BH];
      float4 v2 = *(const float4*)&part[base + 2 * BH];
      float4 v3 = *(const float4*)&part[base + 3 * BH];
      float4 bi = *(const float4*)&bb0[kb + c4 * 4];
      At[c4 * 4 + 0][m] = fmaxf(v0.x + v1.x + v2.x + v3.x + bi.x, 0.f);
      At[c4 * 4 + 1][m] = fmaxf(v0.y + v1.y + v2.y + v3.y + bi.y, 0.f);
      At[c4 * 4 + 2][m] = fmaxf(v0.z + v1.z + v2.z + v3.z + bi.z, 0.f);
      At[c4 * 4 + 3][m] = fmaxf(v0.w + v1.w + v2.w + v3.w + bi.w, 0.f);
    }
    {
      int m = t >> 3, c4 = t & 7;
      if (m < 32) {
        float4 v = *(const float4*)&Bm[(size_t)(n0 + m) * H_N + kb + c4 * 4];
        Bt[c4 * 4 + 0][m] = v.x;
        Bt[c4 * 4 + 1][m] = v.y;
        Bt[c4 * 4 + 2][m] = v.z;
        Bt[c4 * 4 + 3][m] = v.w;
      }
    }
    __syncthreads();
#pragma unroll
    for (int k = 0; k < 32; ++k) {
      float2 av = *(const float2*)&At[k][tmq * 2];
      float4 bv = *(const float4*)&Bt[k][tn * 4];
      acc[0][0] += av.x * bv.x; acc[0][1] += av.x * bv.y;
      acc[0][2] += av.x * bv.z; acc[0][3] += av.x * bv.w;
      acc[1][0] += av.y * bv.x; acc[1][1] += av.y * bv.y;
      acc[1][2] += av.y * bv.z; acc[1][3] += av.y * bv.w;
    }
    __syncthreads();
  }
#pragma unroll
  for (int ii = 0; ii < 2; ++ii) {
    int m = m0 + tmq * 2 + ii;
    float* o = h1 + (size_t)m * H_N + n0 + tn * 4;
    float4 v;
    v.x = fmaxf(acc[ii][0] + bias[n0 + tn * 4 + 0], 0.f);
    v.y = fmaxf(acc[ii][1] + bias[n0 + tn * 4 + 1], 0.f);
    v.z = fmaxf(acc[ii][2] + bias[n0 + tn * 4 + 2], 0.f);
    v.w = fmaxf(acc[ii][3] + bias[n0 + tn * 4 + 3], 0.f);
    *(float4*)o = v;
  }
}

// ---------------------------------------------------------------------------
// Kernel 5: out[b,:] = h1[b,:] @ Wout^T + bout. One wave per batch row.
// ---------------------------------------------------------------------------
__global__ __launch_bounds__(256) void k_out(const float* __restrict__ h1,
                                             const float* __restrict__ Wout,
                                             const float* __restrict__ bout,
                                             float* __restrict__ out) {
  int w = threadIdx.x >> 6, lane = threadIdx.x & 63;
  int b = blockIdx.x * 4 + w;
  const float* hr = h1 + (size_t)b * H_N;
  float h[4];
#pragma unroll
  for (int j = 0; j < 4; ++j) h[j] = hr[lane + 64 * j];
  float acc[10];
#pragma unroll
  for (int o = 0; o < 10; ++o) {
    float s = 0.f;
#pragma unroll
    for (int j = 0; j < 4; ++j) s += h[j] * Wout[o * H_N + lane + 64 * j];
#pragma unroll
    for (int m = 32; m >= 1; m >>= 1) s += __shfl_xor(s, m);
    acc[o] = s;
  }
  if (lane == 0) {
#pragma unroll
    for (int o = 0; o < 10; ++o) out[(size_t)b * O_N + o] = acc[o] + bout[o];
  }
}

// ---------------------------------------------------------------------------
extern "C" void kernel_launch(void* const* d_in, const int* in_sizes, int n_in,
                              void* d_out, int out_size, void* d_ws,
                              size_t ws_size, hipStream_t stream) {
  (void)in_sizes; (void)n_in; (void)out_size; (void)ws_size;
  const float* x    = (const float*)d_in[0];
  const float* W    = (const float*)d_in[1];
  const float* bvec = (const float*)d_in[2];
  const float* Wb0  = (const float*)d_in[3];
  const float* bb0  = (const float*)d_in[4];
  const float* Wb1  = (const float*)d_in[5];
  const float* bb1  = (const float*)d_in[6];
  const float* Wout = (const float*)d_in[7];
  const float* bout = (const float*)d_in[8];

  float* out   = (float*)d_out;     // B*10
  float* masks = out + B_SZ * O_N;  // B*48

  char* wsb = (char*)d_ws;
  float* P = (float*)wsb;                                   // 393,216 B
  unsigned short* Ch = (unsigned short*)(wsb + 393216);     // B*KPAD2 us
  unsigned short* Cl = Ch + (size_t)B_SZ * KPAD2;
  unsigned short* Gh = Cl + (size_t)B_SZ * KPAD2;           // H*KPAD2 us
  unsigned short* Gl = Gh + (size_t)H_N * KPAD2;
  float* part = (float*)(Gl + (size_t)H_N * KPAD2);         // 4*B*H f32
  float* Gp = part + 4 * (size_t)B_SZ * H_N;                // 4*H*KC f32
  float* h1 = Gp;                                           // alias (Gp dead)
  // total ~30 MB

  k_phase1<<<dim3(1152), 256, 0, stream>>>(W, Wb0, x, Gp, P);
  k_mid<<<dim3(768), 256, 0, stream>>>(Gp, Wb0, W, bvec, P, Gh, Gl, Ch, Cl,
                                       masks);
  k_gemm_bf16<<<dim3(32, 4, 4), 256, 0, stream>>>(Ch, Cl, Gh, Gl, part);
  k_gemm2f<<<dim3(32, 8), 256, 0, stream>>>(part, bb0, Wb1, bb1, h1);
  k_out<<<dim3(512), 256, 0, stream>>>(h1, Wout, bout, out);
}

// Round 11
// 64.902 us; speedup vs baseline: 1.3964x; 1.1684x over previous
//
#include <hip/hip_runtime.h>

#define B_SZ 2048
#define D_IN 256
#define L_N 48
#define H_N 256
#define O_N 10
#define WROW 303      // D + L - 1
#define LEAF_N 12336  // L*(D+1)
#define KC 2304       // L*L (Gp full layout)
#define KTRI 1176     // 48*49/2 packed lower-tri cols
#define KH2 1224      // KTRI + 48 offs cols
#define KPAD2 1280    // padded K (20 x 64)

using short8 = __attribute__((ext_vector_type(8))) short;
using f32x4  = __attribute__((ext_vector_type(4))) float;

// split fp32 into bf16 hi (truncate) + bf16 lo (truncate of residual)
__device__ inline void bf16_split(float v, unsigned short& h, unsigned short& l) {
  unsigned bits = __float_as_uint(v);
  h = (unsigned short)(bits >> 16);
  float hf = __uint_as_float(bits & 0xFFFF0000u);
  float r = v - hf;
  l = (unsigned short)(__float_as_uint(r) >> 16);
}
__device__ inline unsigned short bf16_hi(float v) {
  return (unsigned short)(__float_as_uint(v) >> 16);
}

// ---------------------------------------------------------------------------
// Kernel 1: merged phase-1. blocks [0,768): Ghat partial GEMM
//   Gp[z][h][i*48+k] = sum_{d in chunk z} W[k,d]*Wb0[h,i*257+d]
// blocks [768,1152): P[b,i] = dot(x[b,:], W[i,0:256])
// ---------------------------------------------------------------------------
__global__ __launch_bounds__(256) void k_phase1(const float* __restrict__ W,
                                                const float* __restrict__ Wb0,
                                                const float* __restrict__ x,
                                                float* __restrict__ Gp,
                                                float* __restrict__ P) {
  const int bid = blockIdx.x;
  const int t = threadIdx.x;
  if (bid < 768) {
    const int i  = bid % 48;              // layer
    const int rest = bid / 48;            // 0..15
    const int h0 = (rest & 3) * 64;       // h tile
    const int dc = (rest >> 2) * 64;      // d chunk
    __shared__ float At[64][68];          // [d][h]
    __shared__ float Bt[64][68];          // [d][k] (k>=48 zero)
    const int tn = t & 15, tm = t >> 4;
    const int sr = t & 3, sc = t >> 2;    // staging: 4 rows x 64 cols
#pragma unroll
    for (int j = 0; j < 16; ++j) {
      int r = sr + j * 4;
      At[sc][r] = Wb0[(size_t)(h0 + r) * LEAF_N + i * 257 + dc + sc];
      Bt[sc][r] = (r < 48) ? W[r * WROW + dc + sc] : 0.f;
    }
    __syncthreads();
    float acc[4][4] = {};
#pragma unroll 8
    for (int d = 0; d < 64; ++d) {
      float4 av = *(const float4*)&At[d][tm * 4];
      float4 bv = *(const float4*)&Bt[d][tn * 4];
      float aa[4] = {av.x, av.y, av.z, av.w};
      float bb[4] = {bv.x, bv.y, bv.z, bv.w};
#pragma unroll
      for (int ii = 0; ii < 4; ++ii)
#pragma unroll
        for (int jj = 0; jj < 4; ++jj) acc[ii][jj] += aa[ii] * bb[jj];
    }
    if (tn < 12) {
      float* gz = Gp + (size_t)(rest >> 2) * (H_N * KC);
#pragma unroll
      for (int ii = 0; ii < 4; ++ii)
        *(float4*)&gz[(size_t)(h0 + tm * 4 + ii) * KC + i * 48 + tn * 4] =
            make_float4(acc[ii][0], acc[ii][1], acc[ii][2], acc[ii][3]);
    }
  } else {
    int idx = (bid - 768) * 256 + t;  // 0..98303
    int b = idx / 48, i = idx - b * 48;
    const float* xr = x + (size_t)b * D_IN;
    const float* wr = W + (size_t)i * WROW;
    float acc = 0.f;
#pragma unroll 4
    for (int d = 0; d < 256; ++d) acc += xr[d] * wr[d];
    P[idx] = acc;
  }
}

// ---------------------------------------------------------------------------
// Kernel 2: merged mid-phase.
// blocks [0,256): gcomb -- sum Gp partials, pack lower-tri j=i(i+1)/2+k,
//                 bf16-HI-only Ghat (+offs col, pad)
// blocks [256,768): seq -- 4 independent waves, one batch row each
// ---------------------------------------------------------------------------
__global__ __launch_bounds__(256) void k_mid(const float* __restrict__ Gp,
                                             const float* __restrict__ Wb0,
                                             const float* __restrict__ W,
                                             const float* __restrict__ bvec,
                                             const float* __restrict__ P,
                                             unsigned short* __restrict__ Gh,
                                             unsigned short* __restrict__ Ch,
                                             unsigned short* __restrict__ Cl,
                                             float* __restrict__ mask_out) {
  const int bid = blockIdx.x;
  const int t = threadIdx.x;
  if (bid < 256) {
    const int h = bid;
    for (int j = t; j < KTRI; j += 256) {
      // j -> (i,k), k<=i
      int i = (int)((sqrtf((float)(8 * j + 1)) - 1.f) * 0.5f);
      while ((i + 1) * (i + 2) / 2 <= j) ++i;
      while (i * (i + 1) / 2 > j) --i;
      int k = j - i * (i + 1) / 2;
      size_t g = (size_t)h * KC + i * 48 + k;
      float v = Gp[g] + Gp[(size_t)H_N * KC + g] +
                Gp[2 * (size_t)H_N * KC + g] + Gp[3 * (size_t)H_N * KC + g];
      Gh[(size_t)h * KPAD2 + j] = bf16_hi(v);
    }
    if (t < 48) {  // offs col
      Gh[(size_t)h * KPAD2 + KTRI + t] =
          bf16_hi(Wb0[(size_t)h * LEAF_N + t * 257 + 256]);
    }
    for (int e = KH2 + t; e < KPAD2; e += 256) Gh[(size_t)h * KPAD2 + e] = 0;
    return;
  }
  // ---- seq part: wave-independent, one batch row per wave ----
  const int b = (bid - 256) * 4 + (t >> 6);
  const int lane = t & 63;

  float whr[47];
#pragma unroll
  for (int k = 0; k < 47; ++k)
    whr[k] = (lane < 48) ? W[lane * WROW + 256 + k] : 0.f;

  float Preg = (lane < 48) ? P[b * 48 + lane] : 0.f;
  float Pb = Preg + ((lane < 48) ? bvec[lane] : 0.f);

  float accA = 0.f, accB = 0.f;
  float offs_lane = 0.f;
  int d_lane = 0;
#pragma unroll
  for (int i = 0; i < 48; ++i) {
    float z = Pb + accA;
    float u = Preg + accB;
    float a_i = fmaxf(z, 0.f);
    bool dpos = z > 0.f;
    float o_i = dpos ? u : 0.f;
    if (lane == i) {
      d_lane = dpos ? 1 : 0;
      offs_lane = a_i - o_i;
    }
    float ab = __shfl(a_i, i);
    float ob = __shfl(o_i, i);
    if (i < 47) {
      accA += whr[i] * ab;
      accB += whr[i] * ob;
    }
  }
  unsigned long long dmask = __ballot(d_lane);

  float s[48];
  s[0] = ((dmask & 1ULL) && lane == 0) ? 1.f : 0.f;
#pragma unroll
  for (int i = 1; i < 48; ++i) {
    if ((dmask >> i) & 1ULL) {
      const float* wrow = W + i * WROW + 256;  // wave-uniform scalar loads
      float t0 = (lane == i) ? 1.f : 0.f;
      float t1 = 0.f, t2 = 0.f, t3 = 0.f;
      int k = 0;
#pragma unroll
      for (; k + 3 < i; k += 4) {
        t0 += wrow[k + 0] * s[k + 0];
        t1 += wrow[k + 1] * s[k + 1];
        t2 += wrow[k + 2] * s[k + 2];
        t3 += wrow[k + 3] * s[k + 3];
      }
#pragma unroll
      for (; k < i; ++k) t0 += wrow[k] * s[k];
      s[i] = (t0 + t1) + (t2 + t3);
    } else {
      s[i] = 0.f;
    }
  }

  // packed stores: for i >= lane, j = i(i+1)/2 + lane (coalesced per i)
  size_t base = (size_t)b * KPAD2;
  if (lane < 48) {
#pragma unroll
    for (int i = 0; i < 48; ++i) {
      if (lane <= i) {
        unsigned short h, l;
        bf16_split(s[i], h, l);
        Ch[base + i * (i + 1) / 2 + lane] = h;
        Cl[base + i * (i + 1) / 2 + lane] = l;
      }
    }
    unsigned short h, l;
    bf16_split(offs_lane, h, l);
    Ch[base + KTRI + lane] = h;
    Cl[base + KTRI + lane] = l;
    mask_out[b * 48 + lane] = d_lane ? 1.f : 0.f;
  }
  for (int e = KH2 + lane; e < KPAD2; e += 64) {
    Ch[base + e] = 0;
    Cl[base + e] = 0;
  }
}

// ---------------------------------------------------------------------------
// Kernel 3: big GEMM, 2-term bf16 MFMA: acc = Ah*Bh + Al*Bh  (B hi-only;
// B=Ghat entries ~0.06 so bf16 trunc err ~1e-3 total -- within budget).
// 4 waves, LDS-staged, LDSP=88. K=1280 split 4x320. XCD-chunk-swizzled.
// ---------------------------------------------------------------------------
#define LDSP 88
__global__ __launch_bounds__(256) void k_gemm_bf16(
    const unsigned short* __restrict__ Ah, const unsigned short* __restrict__ Al,
    const unsigned short* __restrict__ Bh,
    float* __restrict__ part) {
  int flat = blockIdx.x + 32 * blockIdx.y + 128 * blockIdx.z;  // 0..511
  int id = (flat & 7) * 64 + (flat >> 3);                      // XCD chunks
  const int bz = id & 3, by = (id >> 2) & 3, bx = id >> 4;
  const int m0 = bx * 64;
  const int n0 = by * 64;
  const int k0 = bz * 320;
  float* dst = part + (size_t)bz * ((size_t)B_SZ * H_N);
  __shared__ unsigned short AhL[64 * LDSP], AlL[64 * LDSP];
  __shared__ unsigned short BhL[64 * LDSP];
  const int t = threadIdx.x;
  const int lane = t & 63;
  const int w = t >> 6;
  const int fr = lane & 15;
  const int fq = lane >> 4;
  f32x4 acc[4] = {};
  for (int it = 0; it < 5; ++it) {
    int kb = k0 + it * 64;
#pragma unroll
    for (int j = 0; j < 2; ++j) {
      int c = t + j * 256;
      int row = c >> 3, ko = (c & 7) * 8;
      size_t ga = (size_t)(m0 + row) * KPAD2 + kb + ko;
      size_t gb = (size_t)(n0 + row) * KPAD2 + kb + ko;
      *(short8*)&AhL[row * LDSP + ko] = *(const short8*)&Ah[ga];
      *(short8*)&AlL[row * LDSP + ko] = *(const short8*)&Al[ga];
      *(short8*)&BhL[row * LDSP + ko] = *(const short8*)&Bh[gb];
    }
    __syncthreads();
#pragma unroll
    for (int ks = 0; ks < 2; ++ks) {
      int aoff = (w * 16 + fr) * LDSP + fq * 8 + ks * 32;
      short8 ah = *(const short8*)&AhL[aoff];
      short8 al = *(const short8*)&AlL[aoff];
#pragma unroll
      for (int nt = 0; nt < 4; ++nt) {
        int boff = (nt * 16 + fr) * LDSP + fq * 8 + ks * 32;
        short8 bh = *(const short8*)&BhL[boff];
        acc[nt] = __builtin_amdgcn_mfma_f32_16x16x32_bf16(ah, bh, acc[nt], 0, 0, 0);
        acc[nt] = __builtin_amdgcn_mfma_f32_16x16x32_bf16(al, bh, acc[nt], 0, 0, 0);
      }
    }
    __syncthreads();
  }
  // C layout: col = lane&15, row = (lane>>4)*4 + reg  [m89-verified]
  int mrow = m0 + w * 16 + fq * 4;
#pragma unroll
  for (int nt = 0; nt < 4; ++nt) {
    int ncol = n0 + nt * 16 + fr;
#pragma unroll
    for (int r = 0; r < 4; ++r)
      dst[(size_t)(mrow + r) * H_N + ncol] = acc[nt][r];
  }
}

// ---------------------------------------------------------------------------
// Kernel 4: h1 = relu( relu(sum_z part_z + bb0) @ Wb1^T + bb1 ) via bf16
// MFMA (single-term; h0,Wb1 ~O(1) so err ~2e-3). Fused reduce+bias+relu+
// bf16-convert in A-staging. BM=64 BN=32, 4 waves. XCD-chunk-swizzled.
// ---------------------------------------------------------------------------
#define LDSP2 72
__global__ __launch_bounds__(256) void k_gemm2b(const float* __restrict__ part,
                                                const float* __restrict__ bb0,
                                                const float* __restrict__ Bm,
                                                const float* __restrict__ bias,
                                                float* __restrict__ h1) {
  int flat = blockIdx.x + 32 * blockIdx.y;      // 0..255
  int id = (flat & 7) * 32 + (flat >> 3);       // XCD chunks, x slowest
  const int m0 = (id >> 3) * 64;
  const int n0 = (id & 7) * 32;
  const size_t BH = (size_t)B_SZ * H_N;
  __shared__ unsigned short AtL[64 * LDSP2];
  __shared__ unsigned short BtL[32 * LDSP2];
  const int t = threadIdx.x;
  const int lane = t & 63;
  const int w = t >> 6;
  const int fr = lane & 15;
  const int fq = lane >> 4;
  f32x4 acc[2] = {};
  for (int it = 0; it < 4; ++it) {
    int kb = it * 64;
    // A: 64 rows x 64 k: reduce 4 parts + bias, relu, bf16
#pragma unroll
    for (int j = 0; j < 4; ++j) {
      int g = t + j * 256;          // 1024 float4-groups
      int row = g >> 4, c4 = g & 15;
      size_t base = (size_t)(m0 + row) * H_N + kb + c4 * 4;
      float4 v0 = *(const float4*)&part[base];
      float4 v1 = *(const float4*)&part[base + BH];
      float4 v2 = *(const float4*)&part[base + 2 * BH];
      float4 v3 = *(const float4*)&part[base + 3 * BH];
      float4 bi = *(const float4*)&bb0[kb + c4 * 4];
      ushort4 o;
      o.x = bf16_hi(fmaxf(v0.x + v1.x + v2.x + v3.x + bi.x, 0.f));
      o.y = bf16_hi(fmaxf(v0.y + v1.y + v2.y + v3.y + bi.y, 0.f));
      o.z = bf16_hi(fmaxf(v0.z + v1.z + v2.z + v3.z + bi.z, 0.f));
      o.w = bf16_hi(fmaxf(v0.w + v1.w + v2.w + v3.w + bi.w, 0.f));
      *(ushort4*)&AtL[row * LDSP2 + c4 * 4] = o;
    }
    // B: 32 rows x 64 k of Wb1 -> bf16
#pragma unroll
    for (int j = 0; j < 2; ++j) {
      int g = t + j * 256;          // 512 float4-groups
      int row = g >> 4, c4 = g & 15;
      float4 v = *(const float4*)&Bm[(size_t)(n0 + row) * H_N + kb + c4 * 4];
      ushort4 o;
      o.x = bf16_hi(v.x); o.y = bf16_hi(v.y);
      o.z = bf16_hi(v.z); o.w = bf16_hi(v.w);
      *(ushort4*)&BtL[row * LDSP2 + c4 * 4] = o;
    }
    __syncthreads();
#pragma unroll
    for (int ks = 0; ks < 2; ++ks) {
      short8 a8 = *(const short8*)&AtL[(w * 16 + fr) * LDSP2 + fq * 8 + ks * 32];
#pragma unroll
      for (int nt = 0; nt < 2; ++nt) {
        short8 b8 =
            *(const short8*)&BtL[(nt * 16 + fr) * LDSP2 + fq * 8 + ks * 32];
        acc[nt] = __builtin_amdgcn_mfma_f32_16x16x32_bf16(a8, b8, acc[nt], 0, 0, 0);
      }
    }
    __syncthreads();
  }
  int mrow = m0 + w * 16 + fq * 4;
#pragma unroll
  for (int nt = 0; nt < 2; ++nt) {
    int ncol = n0 + nt * 16 + fr;
    float bs = bias[ncol];
#pragma unroll
    for (int r = 0; r < 4; ++r)
      h1[(size_t)(mrow + r) * H_N + ncol] = fmaxf(acc[nt][r] + bs, 0.f);
  }
}

// ---------------------------------------------------------------------------
// Kernel 5: out[b,:] = h1[b,:] @ Wout^T + bout. One wave per batch row.
// ---------------------------------------------------------------------------
__global__ __launch_bounds__(256) void k_out(const float* __restrict__ h1,
                                             const float* __restrict__ Wout,
                                             const float* __restrict__ bout,
                                             float* __restrict__ out) {
  int w = threadIdx.x >> 6, lane = threadIdx.x & 63;
  int b = blockIdx.x * 4 + w;
  const float* hr = h1 + (size_t)b * H_N;
  float h[4];
#pragma unroll
  for (int j = 0; j < 4; ++j) h[j] = hr[lane + 64 * j];
  float acc[10];
#pragma unroll
  for (int o = 0; o < 10; ++o) {
    float s = 0.f;
#pragma unroll
    for (int j = 0; j < 4; ++j) s += h[j] * Wout[o * H_N + lane + 64 * j];
#pragma unroll
    for (int m = 32; m >= 1; m >>= 1) s += __shfl_xor(s, m);
    acc[o] = s;
  }
  if (lane == 0) {
#pragma unroll
    for (int o = 0; o < 10; ++o) out[(size_t)b * O_N + o] = acc[o] + bout[o];
  }
}

// ---------------------------------------------------------------------------
extern "C" void kernel_launch(void* const* d_in, const int* in_sizes, int n_in,
                              void* d_out, int out_size, void* d_ws,
                              size_t ws_size, hipStream_t stream) {
  (void)in_sizes; (void)n_in; (void)out_size; (void)ws_size;
  const float* x    = (const float*)d_in[0];
  const float* W    = (const float*)d_in[1];
  const float* bvec = (const float*)d_in[2];
  const float* Wb0  = (const float*)d_in[3];
  const float* bb0  = (const float*)d_in[4];
  const float* Wb1  = (const float*)d_in[5];
  const float* bb1  = (const float*)d_in[6];
  const float* Wout = (const float*)d_in[7];
  const float* bout = (const float*)d_in[8];

  float* out   = (float*)d_out;     // B*10
  float* masks = out + B_SZ * O_N;  // B*48

  char* wsb = (char*)d_ws;
  float* P = (float*)wsb;                                   // 393,216 B
  unsigned short* Ch = (unsigned short*)(wsb + 393216);     // B*KPAD2 us
  unsigned short* Cl = Ch + (size_t)B_SZ * KPAD2;
  unsigned short* Gh = Cl + (size_t)B_SZ * KPAD2;           // H*KPAD2 us
  float* part = (float*)(Gh + (size_t)H_N * KPAD2);         // 4*B*H f32
  float* Gp = part + 4 * (size_t)B_SZ * H_N;                // 4*H*KC f32
  float* h1 = Gp;                                           // alias (Gp dead)
  // total ~29 MB

  k_phase1<<<dim3(1152), 256, 0, stream>>>(W, Wb0, x, Gp, P);
  k_mid<<<dim3(768), 256, 0, stream>>>(Gp, Wb0, W, bvec, P, Gh, Ch, Cl,
                                       masks);
  k_gemm_bf16<<<dim3(32, 4, 4), 256, 0, stream>>>(Ch, Cl, Gh, part);
  k_gemm2b<<<dim3(32, 8), 256, 0, stream>>>(part, bb0, Wb1, bb1, h1);
  k_out<<<dim3(512), 256, 0, stream>>>(h1, Wout, bout, out);
}

// Round 12
// 61.911 us; speedup vs baseline: 1.4639x; 1.0483x over previous
//
#include <hip/hip_runtime.h>

#define B_SZ 2048
#define D_IN 256
#define L_N 48
#define H_N 256
#define O_N 10
#define WROW 303      // D + L - 1
#define LEAF_N 12336  // L*(D+1)
#define KTRI 1176     // 48*49/2 packed lower-tri cols
#define KH2 1224      // KTRI + 48 offs cols
#define KPAD2 1280    // padded K (20 x 64)

using short8 = __attribute__((ext_vector_type(8))) short;
using f32x4  = __attribute__((ext_vector_type(4))) float;

__device__ inline void bf16_split(float v, unsigned short& h, unsigned short& l) {
  unsigned bits = __float_as_uint(v);
  h = (unsigned short)(bits >> 16);
  float hf = __uint_as_float(bits & 0xFFFF0000u);
  float r = v - hf;
  l = (unsigned short)(__float_as_uint(r) >> 16);
}
__device__ inline unsigned short bf16_hi(float v) {
  return (unsigned short)(__float_as_uint(v) >> 16);
}

// ---------------------------------------------------------------------------
// Kernel 1 (merged front-end, 704 blocks):
// blocks [0,192): ghat-full -- per (i, h-tile): Gh[h, tri(i)+k] (k<=i) via
//   full-K=256 GEMM in 4 staged rounds; wave w owns k-cols [16w,16w+16) and
//   is SKIPPED when 16w > i (lower-tri only). + offs col + pad (i==0).
// blocks [192,704): seq -- 4 waves, one batch row each; P computed in-wave
//   (lane i serial-dots W[i,:]*x[b,:]; x reads wave-uniform -> s_loads),
//   then z/u recurrences, S-column solve, packed-tri bf16 hi/lo Chat.
// ---------------------------------------------------------------------------
__global__ __launch_bounds__(256) void k1(const float* __restrict__ W,
                                          const float* __restrict__ Wb0,
                                          const float* __restrict__ x,
                                          const float* __restrict__ bvec,
                                          unsigned short* __restrict__ Gh,
                                          unsigned short* __restrict__ Ch,
                                          unsigned short* __restrict__ Cl,
                                          float* __restrict__ mask_out) {
  const int bid = blockIdx.x;
  const int t = threadIdx.x;
  __shared__ float At[64][68];  // [d][h]
  __shared__ float Bt[64][68];  // [d][k] (k>=48 zero)
  if (bid < 192) {
    const int i  = bid % 48;
    const int h0 = (bid / 48) * 64;
    const int w = t >> 6;        // wave -> k-group [16w, 16w+16)
    const int lane = t & 63;
    const int hq = lane & 15;    // h quad (rows hq*4..+3)
    const int kq = lane >> 4;    // k quad within group
    const int sr = t & 3, sc = t >> 2;
    const bool wactive = (16 * w) <= i;
    float acc[4][4] = {};
    for (int dc = 0; dc < 256; dc += 64) {
      __syncthreads();
#pragma unroll
      for (int j = 0; j < 16; ++j) {
        int r = sr + j * 4;
        At[sc][r] = Wb0[(size_t)(h0 + r) * LEAF_N + i * 257 + dc + sc];
        Bt[sc][r] = (r < 48) ? W[r * WROW + dc + sc] : 0.f;
      }
      __syncthreads();
      if (wactive) {
#pragma unroll 8
        for (int d = 0; d < 64; ++d) {
          float4 av = *(const float4*)&At[d][hq * 4];
          float4 bv = *(const float4*)&Bt[d][w * 16 + kq * 4];
          float aa[4] = {av.x, av.y, av.z, av.w};
          float bb[4] = {bv.x, bv.y, bv.z, bv.w};
#pragma unroll
          for (int ii = 0; ii < 4; ++ii)
#pragma unroll
            for (int jj = 0; jj < 4; ++jj) acc[ii][jj] += aa[ii] * bb[jj];
        }
      }
    }
    if (wactive) {
      int tb = i * (i + 1) / 2;
#pragma unroll
      for (int ii = 0; ii < 4; ++ii) {
        size_t hrow = (size_t)(h0 + hq * 4 + ii) * KPAD2;
#pragma unroll
        for (int jj = 0; jj < 4; ++jj) {
          int k = w * 16 + kq * 4 + jj;
          if (k <= i) Gh[hrow + tb + k] = bf16_hi(acc[ii][jj]);
        }
      }
    }
    if (t < 64)  // offs column for this i
      Gh[(size_t)(h0 + t) * KPAD2 + KTRI + i] =
          bf16_hi(Wb0[(size_t)(h0 + t) * LEAF_N + i * 257 + 256]);
    if (i == 0) {  // pad [KH2, KPAD2)
      for (int e = t; e < 64 * (KPAD2 - KH2); e += 256) {
        int r = e / (KPAD2 - KH2), c = e - r * (KPAD2 - KH2);
        Gh[(size_t)(h0 + r) * KPAD2 + KH2 + c] = 0;
      }
    }
    return;
  }
  // ---- seq: 4 independent waves, one batch row per wave ----
  const int b = (bid - 192) * 4 + (t >> 6);
  const int lane = t & 63;

  // in-wave P: lane i = dot(x[b,:], W[i,0:256]); x loads wave-uniform
  float Preg = 0.f;
  if (lane < 48) {
    const float* xr = x + (size_t)b * D_IN;
    const float* wr = W + lane * WROW;
    float a0 = 0.f, a1 = 0.f, a2 = 0.f, a3 = 0.f;
#pragma unroll 4
    for (int d = 0; d < 256; d += 4) {
      a0 = fmaf(xr[d + 0], wr[d + 0], a0);
      a1 = fmaf(xr[d + 1], wr[d + 1], a1);
      a2 = fmaf(xr[d + 2], wr[d + 2], a2);
      a3 = fmaf(xr[d + 3], wr[d + 3], a3);
    }
    Preg = (a0 + a1) + (a2 + a3);
  }

  float whr[47];
#pragma unroll
  for (int k = 0; k < 47; ++k)
    whr[k] = (lane < 48) ? W[lane * WROW + 256 + k] : 0.f;

  float Pb = Preg + ((lane < 48) ? bvec[lane] : 0.f);

  float accA = 0.f, accB = 0.f;
  float offs_lane = 0.f;
  int d_lane = 0;
#pragma unroll
  for (int i = 0; i < 48; ++i) {
    float z = Pb + accA;
    float u = Preg + accB;
    float a_i = fmaxf(z, 0.f);
    bool dpos = z > 0.f;
    float o_i = dpos ? u : 0.f;
    if (lane == i) {
      d_lane = dpos ? 1 : 0;
      offs_lane = a_i - o_i;
    }
    float ab = __shfl(a_i, i);
    float ob = __shfl(o_i, i);
    if (i < 47) {
      accA += whr[i] * ab;
      accB += whr[i] * ob;
    }
  }
  unsigned long long dmask = __ballot(d_lane);

  float s[48];
  s[0] = ((dmask & 1ULL) && lane == 0) ? 1.f : 0.f;
#pragma unroll
  for (int i = 1; i < 48; ++i) {
    if ((dmask >> i) & 1ULL) {
      const float* wrow = W + i * WROW + 256;  // wave-uniform scalar loads
      float t0 = (lane == i) ? 1.f : 0.f;
      float t1 = 0.f, t2 = 0.f, t3 = 0.f;
      int k = 0;
#pragma unroll
      for (; k + 3 < i; k += 4) {
        t0 += wrow[k + 0] * s[k + 0];
        t1 += wrow[k + 1] * s[k + 1];
        t2 += wrow[k + 2] * s[k + 2];
        t3 += wrow[k + 3] * s[k + 3];
      }
#pragma unroll
      for (; k < i; ++k) t0 += wrow[k] * s[k];
      s[i] = (t0 + t1) + (t2 + t3);
    } else {
      s[i] = 0.f;
    }
  }

  // packed stores: for i >= lane, j = i(i+1)/2 + lane (coalesced per i)
  size_t base = (size_t)b * KPAD2;
  if (lane < 48) {
#pragma unroll
    for (int i = 0; i < 48; ++i) {
      if (lane <= i) {
        unsigned short h, l;
        bf16_split(s[i], h, l);
        Ch[base + i * (i + 1) / 2 + lane] = h;
        Cl[base + i * (i + 1) / 2 + lane] = l;
      }
    }
    unsigned short h, l;
    bf16_split(offs_lane, h, l);
    Ch[base + KTRI + lane] = h;
    Cl[base + KTRI + lane] = l;
    mask_out[b * 48 + lane] = d_lane ? 1.f : 0.f;
  }
  for (int e = KH2 + lane; e < KPAD2; e += 64) {
    Ch[base + e] = 0;
    Cl[base + e] = 0;
  }
}

// ---------------------------------------------------------------------------
// Kernel 2: big GEMM, 2-term bf16 MFMA: acc = Ah*Bh + Al*Bh.
// 4 waves, LDS-staged, LDSP=88. K=1280 split 4x320. XCD-chunk-swizzled.
// ---------------------------------------------------------------------------
#define LDSP 88
__global__ __launch_bounds__(256) void k_gemm_bf16(
    const unsigned short* __restrict__ Ah, const unsigned short* __restrict__ Al,
    const unsigned short* __restrict__ Bh,
    float* __restrict__ part) {
  int flat = blockIdx.x + 32 * blockIdx.y + 128 * blockIdx.z;  // 0..511
  int id = (flat & 7) * 64 + (flat >> 3);                      // XCD chunks
  const int bz = id & 3, by = (id >> 2) & 3, bx = id >> 4;
  const int m0 = bx * 64;
  const int n0 = by * 64;
  const int k0 = bz * 320;
  float* dst = part + (size_t)bz * ((size_t)B_SZ * H_N);
  __shared__ unsigned short AhL[64 * LDSP], AlL[64 * LDSP];
  __shared__ unsigned short BhL[64 * LDSP];
  const int t = threadIdx.x;
  const int lane = t & 63;
  const int w = t >> 6;
  const int fr = lane & 15;
  const int fq = lane >> 4;
  f32x4 acc[4] = {};
  for (int it = 0; it < 5; ++it) {
    int kb = k0 + it * 64;
#pragma unroll
    for (int j = 0; j < 2; ++j) {
      int c = t + j * 256;
      int row = c >> 3, ko = (c & 7) * 8;
      size_t ga = (size_t)(m0 + row) * KPAD2 + kb + ko;
      size_t gb = (size_t)(n0 + row) * KPAD2 + kb + ko;
      *(short8*)&AhL[row * LDSP + ko] = *(const short8*)&Ah[ga];
      *(short8*)&AlL[row * LDSP + ko] = *(const short8*)&Al[ga];
      *(short8*)&BhL[row * LDSP + ko] = *(const short8*)&Bh[gb];
    }
    __syncthreads();
#pragma unroll
    for (int ks = 0; ks < 2; ++ks) {
      int aoff = (w * 16 + fr) * LDSP + fq * 8 + ks * 32;
      short8 ah = *(const short8*)&AhL[aoff];
      short8 al = *(const short8*)&AlL[aoff];
#pragma unroll
      for (int nt = 0; nt < 4; ++nt) {
        int boff = (nt * 16 + fr) * LDSP + fq * 8 + ks * 32;
        short8 bh = *(const short8*)&BhL[boff];
        acc[nt] = __builtin_amdgcn_mfma_f32_16x16x32_bf16(ah, bh, acc[nt], 0, 0, 0);
        acc[nt] = __builtin_amdgcn_mfma_f32_16x16x32_bf16(al, bh, acc[nt], 0, 0, 0);
      }
    }
    __syncthreads();
  }
  // C layout: col = lane&15, row = (lane>>4)*4 + reg  [m89-verified]
  int mrow = m0 + w * 16 + fq * 4;
#pragma unroll
  for (int nt = 0; nt < 4; ++nt) {
    int ncol = n0 + nt * 16 + fr;
#pragma unroll
    for (int r = 0; r < 4; ++r)
      dst[(size_t)(mrow + r) * H_N + ncol] = acc[nt][r];
  }
}

// ---------------------------------------------------------------------------
// Kernel 3: h1 = relu( relu(sum_z part_z + bb0) @ Wb1^T + bb1 ) via bf16
// MFMA; fused reduce+bias+relu+bf16 in A-staging. BM=64 BN=32, 4 waves.
// ---------------------------------------------------------------------------
#define LDSP2 72
__global__ __launch_bounds__(256) void k_gemm2b(const float* __restrict__ part,
                                                const float* __restrict__ bb0,
                                                const float* __restrict__ Bm,
                                                const float* __restrict__ bias,
                                                float* __restrict__ h1) {
  int flat = blockIdx.x + 32 * blockIdx.y;      // 0..255
  int id = (flat & 7) * 32 + (flat >> 3);       // XCD chunks, x slowest
  const int m0 = (id >> 3) * 64;
  const int n0 = (id & 7) * 32;
  const size_t BH = (size_t)B_SZ * H_N;
  __shared__ unsigned short AtL[64 * LDSP2];
  __shared__ unsigned short BtL[32 * LDSP2];
  const int t = threadIdx.x;
  const int lane = t & 63;
  const int w = t >> 6;
  const int fr = lane & 15;
  const int fq = lane >> 4;
  f32x4 acc[2] = {};
  for (int it = 0; it < 4; ++it) {
    int kb = it * 64;
#pragma unroll
    for (int j = 0; j < 4; ++j) {
      int g = t + j * 256;
      int row = g >> 4, c4 = g & 15;
      size_t base = (size_t)(m0 + row) * H_N + kb + c4 * 4;
      float4 v0 = *(const float4*)&part[base];
      float4 v1 = *(const float4*)&part[base + BH];
      float4 v2 = *(const float4*)&part[base + 2 * BH];
      float4 v3 = *(const float4*)&part[base + 3 * BH];
      float4 bi = *(const float4*)&bb0[kb + c4 * 4];
      ushort4 o;
      o.x = bf16_hi(fmaxf(v0.x + v1.x + v2.x + v3.x + bi.x, 0.f));
      o.y = bf16_hi(fmaxf(v0.y + v1.y + v2.y + v3.y + bi.y, 0.f));
      o.z = bf16_hi(fmaxf(v0.z + v1.z + v2.z + v3.z + bi.z, 0.f));
      o.w = bf16_hi(fmaxf(v0.w + v1.w + v2.w + v3.w + bi.w, 0.f));
      *(ushort4*)&AtL[row * LDSP2 + c4 * 4] = o;
    }
#pragma unroll
    for (int j = 0; j < 2; ++j) {
      int g = t + j * 256;
      int row = g >> 4, c4 = g & 15;
      float4 v = *(const float4*)&Bm[(size_t)(n0 + row) * H_N + kb + c4 * 4];
      ushort4 o;
      o.x = bf16_hi(v.x); o.y = bf16_hi(v.y);
      o.z = bf16_hi(v.z); o.w = bf16_hi(v.w);
      *(ushort4*)&BtL[row * LDSP2 + c4 * 4] = o;
    }
    __syncthreads();
#pragma unroll
    for (int ks = 0; ks < 2; ++ks) {
      short8 a8 = *(const short8*)&AtL[(w * 16 + fr) * LDSP2 + fq * 8 + ks * 32];
#pragma unroll
      for (int nt = 0; nt < 2; ++nt) {
        short8 b8 =
            *(const short8*)&BtL[(nt * 16 + fr) * LDSP2 + fq * 8 + ks * 32];
        acc[nt] = __builtin_amdgcn_mfma_f32_16x16x32_bf16(a8, b8, acc[nt], 0, 0, 0);
      }
    }
    __syncthreads();
  }
  int mrow = m0 + w * 16 + fq * 4;
#pragma unroll
  for (int nt = 0; nt < 2; ++nt) {
    int ncol = n0 + nt * 16 + fr;
    float bs = bias[ncol];
#pragma unroll
    for (int r = 0; r < 4; ++r)
      h1[(size_t)(mrow + r) * H_N + ncol] = fmaxf(acc[nt][r] + bs, 0.f);
  }
}

// ---------------------------------------------------------------------------
// Kernel 4: out[b,:] = h1[b,:] @ Wout^T + bout. One wave per batch row.
// ---------------------------------------------------------------------------
__global__ __launch_bounds__(256) void k_out(const float* __restrict__ h1,
                                             const float* __restrict__ Wout,
                                             const float* __restrict__ bout,
                                             float* __restrict__ out) {
  int w = threadIdx.x >> 6, lane = threadIdx.x & 63;
  int b = blockIdx.x * 4 + w;
  const float* hr = h1 + (size_t)b * H_N;
  float h[4];
#pragma unroll
  for (int j = 0; j < 4; ++j) h[j] = hr[lane + 64 * j];
  float acc[10];
#pragma unroll
  for (int o = 0; o < 10; ++o) {
    float s = 0.f;
#pragma unroll
    for (int j = 0; j < 4; ++j) s += h[j] * Wout[o * H_N + lane + 64 * j];
#pragma unroll
    for (int m = 32; m >= 1; m >>= 1) s += __shfl_xor(s, m);
    acc[o] = s;
  }
  if (lane == 0) {
#pragma unroll
    for (int o = 0; o < 10; ++o) out[(size_t)b * O_N + o] = acc[o] + bout[o];
  }
}

// ---------------------------------------------------------------------------
extern "C" void kernel_launch(void* const* d_in, const int* in_sizes, int n_in,
                              void* d_out, int out_size, void* d_ws,
                              size_t ws_size, hipStream_t stream) {
  (void)in_sizes; (void)n_in; (void)out_size; (void)ws_size;
  const float* x    = (const float*)d_in[0];
  const float* W    = (const float*)d_in[1];
  const float* bvec = (const float*)d_in[2];
  const float* Wb0  = (const float*)d_in[3];
  const float* bb0  = (const float*)d_in[4];
  const float* Wb1  = (const float*)d_in[5];
  const float* bb1  = (const float*)d_in[6];
  const float* Wout = (const float*)d_in[7];
  const float* bout = (const float*)d_in[8];

  float* out   = (float*)d_out;     // B*10
  float* masks = out + B_SZ * O_N;  // B*48

  char* wsb = (char*)d_ws;
  unsigned short* Ch = (unsigned short*)wsb;                // B*KPAD2 us
  unsigned short* Cl = Ch + (size_t)B_SZ * KPAD2;
  unsigned short* Gh = Cl + (size_t)B_SZ * KPAD2;           // H*KPAD2 us
  float* part = (float*)(Gh + (size_t)H_N * KPAD2);         // 4*B*H f32
  float* h1 = part + 4 * (size_t)B_SZ * H_N;                // B*H f32
  // total ~22 MB

  k1<<<dim3(704), 256, 0, stream>>>(W, Wb0, x, bvec, Gh, Ch, Cl, masks);
  k_gemm_bf16<<<dim3(32, 4, 4), 256, 0, stream>>>(Ch, Cl, Gh, part);
  k_gemm2b<<<dim3(32, 8), 256, 0, stream>>>(part, bb0, Wb1, bb1, h1);
  k_out<<<dim3(512), 256, 0, stream>>>(h1, Wout, bout, out);
}